// Round 11
// baseline (120.329 us; speedup 1.0000x reference)
//
#include <hip/hip_runtime.h>

// AlignOnlySubLayer: out[b,m,d] = main[b,m,d] - sum_c softmax_m(C·M^T)[c,m] * C[c,d]
// B=8, Lc=Lm=2048, D=128, fp32 in/out.
// Round-11: identical to R10 except attend uses 64-c steps -> LDS 40 KB ->
// 4 blocks/CU (16 waves/CU, 2x latency hiding). Same dbuf hazard pattern.
//   convert: Cbf/Mbf = bf16(ctx/main) swizzled; Lg = 0
//   stats  : E[b,m,c] = bf16(exp(S-40)) reg->global (swizzled); L via atomics
//   prep   : CtL[b,d,c] = bf16(Cbf[b,c,d]*invL) transposed+swizzled
//   attend : out = main - E · CtL  (dbuf async-staged MFMA GEMM, K=2048, 32 steps)
// Swizzle: 16B chunk pc = (lc&8)|((lc^row)&7); frag reads at ((kk)^(row&7))*8.

#define BATCH 8
#define L_SEQ 2048
#define DD 128
#define SHIFT 40.0f
#define LDA 136   // fallback/prep padded stride

typedef __attribute__((ext_vector_type(8))) short bf16x8;
typedef __attribute__((ext_vector_type(4))) short bf16x4;
typedef __attribute__((ext_vector_type(4))) float f32x4;

__device__ __forceinline__ short f2bf(float f) {
    unsigned u = __builtin_bit_cast(unsigned, f);
    return (short)((u + 0x8000u) >> 16);
}
__device__ __forceinline__ float bf2f(short s) {
    unsigned u = ((unsigned)(unsigned short)s) << 16;
    return __builtin_bit_cast(float, u);
}

// Async global->LDS, 16 B per lane. LDS dest = uniform base + lane*16.
__device__ __forceinline__ void gl2lds16(const short* g, short* l) {
    __builtin_amdgcn_global_load_lds(
        (const __attribute__((address_space(1))) unsigned int*)g,
        (__attribute__((address_space(3))) unsigned int*)l, 16, 0, 0);
}

// fp32 global (rows of 128) -> bf16 LDS tile, stride LDA (small-ws fallback only).
template <int NT>
__device__ __forceinline__ void stage_tile(short* __restrict__ dst,
                                           const float* __restrict__ src,
                                           int nelts, int t) {
    for (int base = 0; base < nelts; base += NT * 8) {
        int flat = base + t * 8;
        const float4* p = (const float4*)(src + flat);
        float4 v0 = p[0];
        float4 v1 = p[1];
        bf16x8 s;
        s[0] = f2bf(v0.x); s[1] = f2bf(v0.y); s[2] = f2bf(v0.z); s[3] = f2bf(v0.w);
        s[4] = f2bf(v1.x); s[5] = f2bf(v1.y); s[6] = f2bf(v1.z); s[7] = f2bf(v1.w);
        int row = flat >> 7;
        int col = flat & 127;
        *(bf16x8*)&dst[row * LDA + col] = s;
    }
}

__global__ __launch_bounds__(256) void zero_kernel(float* __restrict__ p, int n) {
    int i = blockIdx.x * 256 + threadIdx.x;
    if (i < n) p[i] = 0.0f;
}

// ---------------------------------------------------------------------------
// Fast path: 4 kernels, 512 blocks x 256 threads each.
// ---------------------------------------------------------------------------

// 512 x 256: four 16B chunks per thread across C and M; also zeros Lg.
__global__ __launch_bounds__(256, 2) void convert_kernel(const float* __restrict__ ctx,
                                                         const float* __restrict__ mn,
                                                         short* __restrict__ Cbf,
                                                         short* __restrict__ Mbf,
                                                         float* __restrict__ Lg) {
    int gtid = blockIdx.x * 256 + threadIdx.x;
    if (gtid < BATCH * L_SEQ) Lg[gtid] = 0.0f;
    const int half = BATCH * L_SEQ * DD / 8;  // 262144 chunks per tensor
    #pragma unroll
    for (int k = 0; k < 4; ++k) {
        int id = gtid + k * (512 * 256);
        const float* src;
        short* dst;
        int iid = id;
        if (iid < half) { src = ctx; dst = Cbf; }
        else            { iid -= half; src = mn; dst = Mbf; }
        int row = iid >> 4;
        int lc = iid & 15;
        const float4* p = (const float4*)(src + ((size_t)row << 7) + lc * 8);
        float4 v0 = p[0];
        float4 v1 = p[1];
        bf16x8 s;
        s[0] = f2bf(v0.x); s[1] = f2bf(v0.y); s[2] = f2bf(v0.z); s[3] = f2bf(v0.w);
        s[4] = f2bf(v1.x); s[5] = f2bf(v1.y); s[6] = f2bf(v1.z); s[7] = f2bf(v1.w);
        int pc = (lc & 8) | ((lc ^ row) & 7);
        *(bf16x8*)&dst[((size_t)row << 7) + pc * 8] = s;
    }
}

// grid = 8 b * 16 ct(128c) * 4 mc(512m) = 512 blocks, 256 thr (4 waves).
// LDS: Cs 32 KB + Ms dbuf 2x16 KB = 64 KB -> 2 blocks/CU (8 waves/CU).
// R8-proven: hoisted C A-frags (64 VGPRs), one barrier per 64-m step, DMA
// into the buffer NOT read this step, E stored straight from registers.
__global__ __launch_bounds__(256, 2) void stats_kernel(const short* __restrict__ Cbf,
                                                       const short* __restrict__ Mbf,
                                                       float* __restrict__ Lg,
                                                       short* __restrict__ Eg) {
    __shared__ short Cs[128 * 128];
    __shared__ short Ms[2][64 * 128];

    int bid = blockIdx.x;
    int mc = bid & 3;
    int ct = (bid >> 2) & 15;
    int b  = bid >> 6;
    int t = threadIdx.x;
    int w = t >> 6;
    int l = t & 63;
    int a15 = l & 15;
    int q = l >> 4;
    int h = a15 & 7;
    int cw = (w & 1) * 64;   // wave c-offset within the 128-c tile
    int mw = (w >> 1) * 32;  // wave m-offset within the 64-m step

    {   // issue Cs (once, 8 insts/wave) + Ms buf0 (step 0, 4 insts/wave)
        const short* gC = Cbf + ((size_t)(b * L_SEQ + ct * 128)) * DD;
        const short* gM = Mbf + ((size_t)(b * L_SEQ + mc * 512)) * DD;
        #pragma unroll
        for (int ii = 0; ii < 8; ++ii) {
            int inst = w * 8 + ii;
            gl2lds16(gC + inst * 512 + l * 8, Cs + inst * 512);
        }
        #pragma unroll
        for (int ii = 0; ii < 4; ++ii) {
            int inst = w * 4 + ii;
            gl2lds16(gM + inst * 512 + l * 8, Ms[0] + inst * 512);
        }
    }

    __syncthreads();  // drains Cs + Ms[0]

    {   // prefetch step-1 M into Ms[1]; flies over the fragment hoist
        const short* gM = Mbf + ((size_t)(b * L_SEQ + mc * 512 + 64)) * DD;
        #pragma unroll
        for (int ii = 0; ii < 4; ++ii) {
            int inst = w * 4 + ii;
            gl2lds16(gM + inst * 512 + l * 8, Ms[1] + inst * 512);
        }
    }

    // Hoist invariant C A-fragments: 16 ds_read_b128 -> 64 VGPRs.
    bf16x8 af[4][4];
    #pragma unroll
    for (int ks = 0; ks < 4; ++ks) {
        int aoff = ((ks * 4 + q) ^ h) * 8;
        #pragma unroll
        for (int i = 0; i < 4; ++i)
            af[ks][i] = *(const bf16x8*)&Cs[(cw + i * 16 + a15) * 128 + aoff];
    }

    float ls[4][4] = {};  // partial L for c = ct*128 + cw + i*16 + q*4 + r

    for (int ms = 0; ms < 8; ++ms) {
        int bp = ms & 1;
        if (ms > 0) {
            __syncthreads();  // drains DMA into Ms[bp] (issued at ms-1)
            if (ms < 7) {     // prefetch next step into the OTHER buffer
                const short* gM = Mbf + ((size_t)(b * L_SEQ + mc * 512 + (ms + 1) * 64)) * DD;
                #pragma unroll
                for (int ii = 0; ii < 4; ++ii) {
                    int inst = w * 4 + ii;
                    gl2lds16(gM + inst * 512 + l * 8, Ms[bp ^ 1] + inst * 512);
                }
            }
        }

        f32x4 acc[4][2];
        #pragma unroll
        for (int i = 0; i < 4; ++i)
            #pragma unroll
            for (int j = 0; j < 2; ++j) {
                f32x4 z = {0.f, 0.f, 0.f, 0.f};
                acc[i][j] = z;
            }
        #pragma unroll
        for (int ks = 0; ks < 4; ++ks) {
            int aoff = ((ks * 4 + q) ^ h) * 8;
            bf16x8 bv[2];
            #pragma unroll
            for (int j = 0; j < 2; ++j)
                bv[j] = *(const bf16x8*)&Ms[bp][(mw + j * 16 + a15) * 128 + aoff];
            #pragma unroll
            for (int i = 0; i < 4; ++i)
                #pragma unroll
                for (int j = 0; j < 2; ++j)
                    acc[i][j] = __builtin_amdgcn_mfma_f32_16x16x32_bf16(af[ks][i], bv[j], acc[i][j], 0, 0, 0);
        }

        // E store straight from registers (b64, swizzled). D layout: row c = q*4+r
        // (4 consecutive c per lane), col m = a15.
        #pragma unroll
        for (int j = 0; j < 2; ++j) {
            int m = mc * 512 + ms * 64 + mw + j * 16 + a15;
            size_t rowb = ((size_t)(b * L_SEQ + m)) * L_SEQ;
            #pragma unroll
            for (int i = 0; i < 4; ++i) {
                bf16x4 pk;
                #pragma unroll
                for (int r = 0; r < 4; ++r) {
                    float e = __expf(acc[i][j][r] - SHIFT);
                    ls[i][r] += e;
                    pk[r] = f2bf(e);
                }
                int cq = ct * 128 + cw + i * 16 + q * 4;
                int chunk = cq >> 3;
                int pcc = (chunk & ~7) | ((chunk ^ m) & 7);
                *(bf16x4*)&Eg[rowb + pcc * 8 + (cq & 7)] = pk;
            }
        }
    }

    #pragma unroll
    for (int i = 0; i < 4; ++i)
        #pragma unroll
        for (int r = 0; r < 4; ++r) {
            float v = ls[i][r];
            v += __shfl_xor(v, 1);
            v += __shfl_xor(v, 2);
            v += __shfl_xor(v, 4);
            v += __shfl_xor(v, 8);
            ls[i][r] = v;
        }
    if (a15 == 0) {
        #pragma unroll
        for (int i = 0; i < 4; ++i) {
            int c = ct * 128 + cw + i * 16 + q * 4;
            #pragma unroll
            for (int r = 0; r < 4; ++r)
                atomicAdd(&Lg[(size_t)b * L_SEQ + c + r], ls[i][r]);
        }
    }
}

// grid = 8 b * 16 cc * 4 dq = 512 blocks, 256 thr. Reads bf16 Cbf.
// CtL[b][d][c] = bf16(C[b][c][d] * invL[b][c]), transposed + swizzled by d&7.
__global__ __launch_bounds__(256, 2) void prep_kernel(const short* __restrict__ Cbf,
                                                      const float* __restrict__ Lg,
                                                      short* __restrict__ CtL) {
    __shared__ short Ts[128 * LDA];
    __shared__ float invLs[128];

    int bid = blockIdx.x;
    int b  = bid >> 6;
    int cc = (bid >> 2) & 15;
    int dq = bid & 3;
    int t = threadIdx.x;

    if (t < 128) invLs[t] = 1.0f / Lg[(size_t)b * L_SEQ + cc * 128 + t];
    __syncthreads();

    // Stage 128x128 tile from Cbf (unswizzle chunks), scale by invL, into Ts.
    #pragma unroll
    for (int it = 0; it < 8; ++it) {
        int cid = it * 256 + t;
        int r = cid >> 4;
        int lcs = cid & 15;                       // stored chunk index
        int lc = (lcs & 8) | ((lcs ^ r) & 7);     // logical chunk (XOR self-inverse)
        bf16x8 v = *(const bf16x8*)&Cbf[((size_t)(b * L_SEQ + cc * 128 + r)) * DD + lcs * 8];
        float il = invLs[r];
        bf16x8 sv;
        #pragma unroll
        for (int j = 0; j < 8; ++j) sv[j] = f2bf(bf2f(v[j]) * il);
        *(bf16x8*)&Ts[r * LDA + lc * 8] = sv;
    }
    __syncthreads();

    // Transposed, swizzled write of this block's 32 d-rows.
    int d = dq * 32 + (t >> 3);
    int key = d & 7;
    #pragma unroll
    for (int it = 0; it < 2; ++it) {
        int chIdx = (t & 7) + 8 * it;  // 0..15
        int c = chIdx * 8;
        bf16x8 v;
        #pragma unroll
        for (int j = 0; j < 8; ++j) v[j] = Ts[(c + j) * LDA + d];
        int pc = cc * 16 + (chIdx & 8) + ((chIdx ^ key) & 7);
        *(bf16x8*)&CtL[((size_t)(b * DD + d)) * L_SEQ + pc * 8] = v;
    }
}

// grid = 512 blocks, 256 thr. 64-c steps: LDS = Et 2x4 KB + Ct 2x16 KB = 40 KB
// -> 4 blocks/CU (16 waves/CU). 32 steps, one barrier each, dbuf hazard pattern.
// Per step per wave: 5 DMA insts (1 Et + 4 Ct), 8 ds_read_b128, 8 MFMA.
__global__ __launch_bounds__(256, 4) void attend_kernel(const short* __restrict__ Eg,
                                                        const short* __restrict__ CtL,
                                                        const float* __restrict__ mn,
                                                        float* __restrict__ out) {
    __shared__ short Et2[2][32 * 64];
    __shared__ short Ct2[2][128 * 64];

    int bid = blockIdx.x;
    int mtile = bid & 63;
    int b = bid >> 6;
    int m0 = mtile * 32;
    int t = threadIdx.x;
    int w = t >> 6;
    int l = t & 63;
    int a15 = l & 15;
    int q = l >> 4;
    int h = a15 & 7;
    int lr = l >> 3;   // 0..7: row within an 8-row DMA instruction
    int lk = l & 7;    // 0..7: 16B chunk within the 128-B row window

    f32x4 acc[2][2] = {{{0.f,0.f,0.f,0.f},{0.f,0.f,0.f,0.f}},
                       {{0.f,0.f,0.f,0.f},{0.f,0.f,0.f,0.f}}};

    // issue buffer 0 (c-window 0): Et 1 inst/wave (rows w*8..w*8+7),
    // Ct 4 insts/wave (d-rows (w*4+ii)*8..+7).
    gl2lds16(Eg + ((size_t)(b * L_SEQ + m0 + w * 8 + lr)) * L_SEQ + lk * 8,
             &Et2[0][w * 512]);
    #pragma unroll
    for (int ii = 0; ii < 4; ++ii) {
        int inst = w * 4 + ii;
        gl2lds16(CtL + ((size_t)(b * DD + inst * 8 + lr)) * L_SEQ + lk * 8,
                 &Ct2[0][inst * 512]);
    }

    for (int cs = 0; cs < 32; ++cs) {
        int bp = cs & 1;
        __syncthreads();  // drains loads into buf bp; buf bp^1 readers done last iter

        if (cs < 31) {  // issue next 64-c window into the other buffer
            int c0 = (cs + 1) * 64;
            gl2lds16(Eg + ((size_t)(b * L_SEQ + m0 + w * 8 + lr)) * L_SEQ + c0 + lk * 8,
                     &Et2[bp ^ 1][w * 512]);
            #pragma unroll
            for (int ii = 0; ii < 4; ++ii) {
                int inst = w * 4 + ii;
                gl2lds16(CtL + ((size_t)(b * DD + inst * 8 + lr)) * L_SEQ + c0 + lk * 8,
                         &Ct2[bp ^ 1][inst * 512]);
            }
        }

        const short* EtB = Et2[bp];
        const short* CtB = Ct2[bp];
        #pragma unroll
        for (int ks = 0; ks < 2; ++ks) {
            int aoff = ((ks * 4 + q) ^ h) * 8;  // kk = ks*4+q in 0..7
            bf16x8 a0 = *(const bf16x8*)&EtB[a15 * 64 + aoff];
            bf16x8 a1 = *(const bf16x8*)&EtB[(16 + a15) * 64 + aoff];
            bf16x8 b0 = *(const bf16x8*)&CtB[((w * 2 + 0) * 16 + a15) * 64 + aoff];
            bf16x8 b1 = *(const bf16x8*)&CtB[((w * 2 + 1) * 16 + a15) * 64 + aoff];
            acc[0][0] = __builtin_amdgcn_mfma_f32_16x16x32_bf16(a0, b0, acc[0][0], 0, 0, 0);
            acc[0][1] = __builtin_amdgcn_mfma_f32_16x16x32_bf16(a0, b1, acc[0][1], 0, 0, 0);
            acc[1][0] = __builtin_amdgcn_mfma_f32_16x16x32_bf16(a1, b0, acc[1][0], 0, 0, 0);
            acc[1][1] = __builtin_amdgcn_mfma_f32_16x16x32_bf16(a1, b1, acc[1][1], 0, 0, 0);
        }
    }

    // Epilogue: out = main(fp32) - O. D: col d = a15, row m = q*4+r.
    #pragma unroll
    for (int mg = 0; mg < 2; ++mg) {
        #pragma unroll
        for (int g = 0; g < 2; ++g) {
            int d = (w * 2 + g) * 16 + a15;
            #pragma unroll
            for (int r = 0; r < 4; ++r) {
                int m = m0 + mg * 16 + q * 4 + r;
                size_t idx = ((size_t)(b * L_SEQ + m)) * DD + d;
                out[idx] = mn[idx] - acc[mg][g][r];
            }
        }
    }
}

// ---------------------------------------------------------------------------
// Small-workspace fallback (round-2 kernels)
// ---------------------------------------------------------------------------

__global__ __launch_bounds__(256, 4) void stats_fb(const float* __restrict__ ctx,
                                                   const float* __restrict__ mn,
                                                   float* __restrict__ Lg) {
    __shared__ short Cs[64 * LDA];
    __shared__ short Ms[64 * LDA];

    int bid = blockIdx.x;
    int mc = bid & 3;
    int ct = (bid >> 2) & 31;
    int b  = bid >> 7;
    int t = threadIdx.x;
    int w = t >> 6;
    int l = t & 63;
    int a15 = l & 15;
    int q = l >> 4;

    stage_tile<256>(Cs, ctx + ((size_t)b * L_SEQ + ct * 64) * DD, 64 * DD, t);

    float ls[4] = {0.f, 0.f, 0.f, 0.f};
    for (int mt = 0; mt < 8; ++mt) {
        __syncthreads();
        int m0 = (mc * 8 + mt) * 64;
        stage_tile<256>(Ms, mn + ((size_t)b * L_SEQ + m0) * DD, 64 * DD, t);
        __syncthreads();

        f32x4 acc[4] = {{0.f,0.f,0.f,0.f},{0.f,0.f,0.f,0.f},{0.f,0.f,0.f,0.f},{0.f,0.f,0.f,0.f}};
        #pragma unroll
        for (int ks = 0; ks < 4; ++ks) {
            int k0 = ks * 32 + q * 8;
            bf16x8 a = *(const bf16x8*)&Cs[(w * 16 + a15) * LDA + k0];
            #pragma unroll
            for (int g = 0; g < 4; ++g) {
                bf16x8 bb = *(const bf16x8*)&Ms[(g * 16 + a15) * LDA + k0];
                acc[g] = __builtin_amdgcn_mfma_f32_16x16x32_bf16(a, bb, acc[g], 0, 0, 0);
            }
        }
        #pragma unroll
        for (int g = 0; g < 4; ++g)
            #pragma unroll
            for (int r = 0; r < 4; ++r)
                ls[r] += __expf(acc[g][r] - SHIFT);
    }

    #pragma unroll
    for (int r = 0; r < 4; ++r) {
        float v = ls[r];
        v += __shfl_xor(v, 1);
        v += __shfl_xor(v, 2);
        v += __shfl_xor(v, 4);
        v += __shfl_xor(v, 8);
        ls[r] = v;
    }
    if (a15 == 0) {
        int c = ct * 64 + w * 16 + q * 4;
        #pragma unroll
        for (int r = 0; r < 4; ++r)
            atomicAdd(&Lg[(size_t)b * L_SEQ + c + r], ls[r]);
    }
}

__global__ __launch_bounds__(1024, 4) void attend_fb(const float* __restrict__ ctx,
                                                     const float* __restrict__ mn,
                                                     const float* __restrict__ Lg,
                                                     float* __restrict__ out) {
    __shared__ short Mt[64 * LDA];
    __shared__ short Cs[128 * LDA];
    __shared__ short Ct[128 * LDA];
    __shared__ short Ps[64 * LDA];
    __shared__ float invLs[128];

    int bid = blockIdx.x;
    int mtile = bid & 31;
    int b = bid >> 5;
    int m0 = mtile * 64;
    int t = threadIdx.x;
    int w = t >> 6;
    int l = t & 63;
    int a15 = l & 15;
    int q = l >> 4;
    int mg = w & 3;
    int pg = w >> 2;

    stage_tile<1024>(Mt, mn + ((size_t)b * L_SEQ + m0) * DD, 64 * DD, t);

    f32x4 oacc[2] = {{0.f,0.f,0.f,0.f},{0.f,0.f,0.f,0.f}};

    for (int cs = 0; cs < 16; ++cs) {
        int c0 = cs * 128;
        __syncthreads();
        stage_tile<1024>(Cs, ctx + ((size_t)b * L_SEQ + c0) * DD, 128 * DD, t);
        if (t < 128) invLs[t] = 1.0f / Lg[(size_t)b * L_SEQ + c0 + t];
        __syncthreads();

        {
            int cc = t & 127;
            int d0 = (t >> 7) * 16;
            #pragma unroll
            for (int hh = 0; hh < 2; ++hh) {
                bf16x8 v = *(const bf16x8*)&Cs[cc * LDA + d0 + hh * 8];
                #pragma unroll
                for (int j = 0; j < 8; ++j)
                    Ct[(d0 + hh * 8 + j) * LDA + cc] = v[j];
            }
        }

        f32x4 sacc[2] = {{0.f,0.f,0.f,0.f},{0.f,0.f,0.f,0.f}};
        #pragma unroll
        for (int ks = 0; ks < 4; ++ks) {
            int k0 = ks * 32 + q * 8;
            bf16x8 a = *(const bf16x8*)&Mt[(mg * 16 + a15) * LDA + k0];
            #pragma unroll
            for (int g = 0; g < 2; ++g) {
                bf16x8 bb = *(const bf16x8*)&Cs[((pg * 2 + g) * 16 + a15) * LDA + k0];
                sacc[g] = __builtin_amdgcn_mfma_f32_16x16x32_bf16(a, bb, sacc[g], 0, 0, 0);
            }
        }
        #pragma unroll
        for (int g = 0; g < 2; ++g) {
            int cl = (pg * 2 + g) * 16 + a15;
            float il = invLs[cl];
            #pragma unroll
            for (int r = 0; r < 4; ++r) {
                float p = __expf(sacc[g][r] - SHIFT) * il;
                Ps[(mg * 16 + q * 4 + r) * LDA + cl] = f2bf(p);
            }
        }
        __syncthreads();

        #pragma unroll
        for (int ks = 0; ks < 4; ++ks) {
            int k0 = ks * 32 + q * 8;
            bf16x8 a = *(const bf16x8*)&Ps[(mg * 16 + a15) * LDA + k0];
            #pragma unroll
            for (int g = 0; g < 2; ++g) {
                bf16x8 bb = *(const bf16x8*)&Ct[((pg * 2 + g) * 16 + a15) * LDA + k0];
                oacc[g] = __builtin_amdgcn_mfma_f32_16x16x32_bf16(a, bb, oacc[g], 0, 0, 0);
            }
        }
    }

    #pragma unroll
    for (int g = 0; g < 2; ++g) {
        int dl = (pg * 2 + g) * 16 + a15;
        #pragma unroll
        for (int r = 0; r < 4; ++r) {
            int ml = mg * 16 + q * 4 + r;
            size_t idx = ((size_t)b * L_SEQ + m0 + ml) * DD + dl;
            out[idx] = mn[idx] - oacc[g][r];
        }
    }
}

// ---------------------------------------------------------------------------

extern "C" void kernel_launch(void* const* d_in, const int* in_sizes, int n_in,
                              void* d_out, int out_size, void* d_ws, size_t ws_size,
                              hipStream_t stream) {
    const float* ctx = (const float*)d_in[0];  // (B, Lc, D)
    const float* mn  = (const float*)d_in[1];  // (B, Lm, D)
    float* out = (float*)d_out;                // (B, Lm, D)

    // Workspace: Lg 64 KB | Cbf 4 MB | Mbf 4 MB | CtL 4 MB | E 67 MB
    const size_t LG_BYTES = (size_t)BATCH * L_SEQ * sizeof(float);
    const size_t BF_BYTES = (size_t)BATCH * L_SEQ * DD * sizeof(short);
    const size_t E_BYTES  = (size_t)BATCH * L_SEQ * L_SEQ * sizeof(short);
    const size_t NEED = LG_BYTES + 3 * BF_BYTES + E_BYTES;

    float* Lg = (float*)d_ws;

    if (ws_size >= NEED) {
        short* Cbf = (short*)((char*)d_ws + LG_BYTES);
        short* Mbf = (short*)((char*)d_ws + LG_BYTES + BF_BYTES);
        short* CtL = (short*)((char*)d_ws + LG_BYTES + 2 * BF_BYTES);
        short* Eg  = (short*)((char*)d_ws + LG_BYTES + 3 * BF_BYTES);
        convert_kernel<<<512, 256, 0, stream>>>(ctx, mn, Cbf, Mbf, Lg);
        stats_kernel<<<512, 256, 0, stream>>>(Cbf, Mbf, Lg, Eg);
        prep_kernel<<<512, 256, 0, stream>>>(Cbf, Lg, CtL);
        attend_kernel<<<512, 256, 0, stream>>>(Eg, CtL, mn, out);
    } else {
        int nL = BATCH * L_SEQ;
        zero_kernel<<<(nL + 255) / 256, 256, 0, stream>>>(Lg, nL);
        stats_fb<<<BATCH * 32 * 4, 256, 0, stream>>>(ctx, mn, Lg);
        attend_fb<<<BATCH * 32, 1024, 0, stream>>>(ctx, mn, Lg, out);
    }
}

// Round 12
// 115.947 us; speedup vs baseline: 1.0378x; 1.0378x over previous
//
#include <hip/hip_runtime.h>

// AlignOnlySubLayer: out[b,m,d] = main[b,m,d] - sum_c softmax_m(C·M^T)[c,m] * C[c,d]
// B=8, Lc=Lm=2048, D=128, fp32 in/out.
// Round-12 == Round-10 (best verified build; R11's 64-c-step attend regressed).
// Split 4-kernel pipeline:
//   convert: Cbf/Mbf = bf16(ctx/main) swizzled; Lg = 0
//   stats  : E[b,m,c] = bf16(exp(S-40)) reg->global (swizzled); L via atomics
//   prep   : CtL[b,d,c] = bf16(Cbf[b,c,d]*invL) transposed+swizzled (reads bf16 Cbf)
//   attend : out = main - E · CtL  (dbuf async-staged MFMA GEMM, K=2048)
// Swizzle: 16B chunk pc = (lc&8)|((lc^row)&7); frag reads at ((ks*4+q)^(a15&7))
// hit exactly 8 words/bank per ds_read_b128.

#define BATCH 8
#define L_SEQ 2048
#define DD 128
#define SHIFT 40.0f
#define LDA 136   // fallback/prep padded stride

typedef __attribute__((ext_vector_type(8))) short bf16x8;
typedef __attribute__((ext_vector_type(4))) short bf16x4;
typedef __attribute__((ext_vector_type(4))) float f32x4;

__device__ __forceinline__ short f2bf(float f) {
    unsigned u = __builtin_bit_cast(unsigned, f);
    return (short)((u + 0x8000u) >> 16);
}
__device__ __forceinline__ float bf2f(short s) {
    unsigned u = ((unsigned)(unsigned short)s) << 16;
    return __builtin_bit_cast(float, u);
}

// Async global->LDS, 16 B per lane. LDS dest = uniform base + lane*16.
__device__ __forceinline__ void gl2lds16(const short* g, short* l) {
    __builtin_amdgcn_global_load_lds(
        (const __attribute__((address_space(1))) unsigned int*)g,
        (__attribute__((address_space(3))) unsigned int*)l, 16, 0, 0);
}

// fp32 global (rows of 128) -> bf16 LDS tile, stride LDA (small-ws fallback only).
template <int NT>
__device__ __forceinline__ void stage_tile(short* __restrict__ dst,
                                           const float* __restrict__ src,
                                           int nelts, int t) {
    for (int base = 0; base < nelts; base += NT * 8) {
        int flat = base + t * 8;
        const float4* p = (const float4*)(src + flat);
        float4 v0 = p[0];
        float4 v1 = p[1];
        bf16x8 s;
        s[0] = f2bf(v0.x); s[1] = f2bf(v0.y); s[2] = f2bf(v0.z); s[3] = f2bf(v0.w);
        s[4] = f2bf(v1.x); s[5] = f2bf(v1.y); s[6] = f2bf(v1.z); s[7] = f2bf(v1.w);
        int row = flat >> 7;
        int col = flat & 127;
        *(bf16x8*)&dst[row * LDA + col] = s;
    }
}

__global__ __launch_bounds__(256) void zero_kernel(float* __restrict__ p, int n) {
    int i = blockIdx.x * 256 + threadIdx.x;
    if (i < n) p[i] = 0.0f;
}

// ---------------------------------------------------------------------------
// Fast path: 4 kernels, 512 blocks x 256 threads each.
// ---------------------------------------------------------------------------

// 512 x 256: four 16B chunks per thread across C and M; also zeros Lg.
__global__ __launch_bounds__(256, 2) void convert_kernel(const float* __restrict__ ctx,
                                                         const float* __restrict__ mn,
                                                         short* __restrict__ Cbf,
                                                         short* __restrict__ Mbf,
                                                         float* __restrict__ Lg) {
    int gtid = blockIdx.x * 256 + threadIdx.x;
    if (gtid < BATCH * L_SEQ) Lg[gtid] = 0.0f;
    const int half = BATCH * L_SEQ * DD / 8;  // 262144 chunks per tensor
    #pragma unroll
    for (int k = 0; k < 4; ++k) {
        int id = gtid + k * (512 * 256);
        const float* src;
        short* dst;
        int iid = id;
        if (iid < half) { src = ctx; dst = Cbf; }
        else            { iid -= half; src = mn; dst = Mbf; }
        int row = iid >> 4;
        int lc = iid & 15;
        const float4* p = (const float4*)(src + ((size_t)row << 7) + lc * 8);
        float4 v0 = p[0];
        float4 v1 = p[1];
        bf16x8 s;
        s[0] = f2bf(v0.x); s[1] = f2bf(v0.y); s[2] = f2bf(v0.z); s[3] = f2bf(v0.w);
        s[4] = f2bf(v1.x); s[5] = f2bf(v1.y); s[6] = f2bf(v1.z); s[7] = f2bf(v1.w);
        int pc = (lc & 8) | ((lc ^ row) & 7);
        *(bf16x8*)&dst[((size_t)row << 7) + pc * 8] = s;
    }
}

// grid = 8 b * 16 ct(128c) * 4 mc(512m) = 512 blocks, 256 thr (4 waves).
// LDS: Cs 32 KB + Ms dbuf 2x16 KB = 64 KB -> 2 blocks/CU (8 waves/CU).
// R8-proven: hoisted C A-frags (64 VGPRs), one barrier per 64-m step, DMA
// into the buffer NOT read this step, E stored straight from registers.
__global__ __launch_bounds__(256, 2) void stats_kernel(const short* __restrict__ Cbf,
                                                       const short* __restrict__ Mbf,
                                                       float* __restrict__ Lg,
                                                       short* __restrict__ Eg) {
    __shared__ short Cs[128 * 128];
    __shared__ short Ms[2][64 * 128];

    int bid = blockIdx.x;
    int mc = bid & 3;
    int ct = (bid >> 2) & 15;
    int b  = bid >> 6;
    int t = threadIdx.x;
    int w = t >> 6;
    int l = t & 63;
    int a15 = l & 15;
    int q = l >> 4;
    int h = a15 & 7;
    int cw = (w & 1) * 64;   // wave c-offset within the 128-c tile
    int mw = (w >> 1) * 32;  // wave m-offset within the 64-m step

    {   // issue Cs (once, 8 insts/wave) + Ms buf0 (step 0, 4 insts/wave)
        const short* gC = Cbf + ((size_t)(b * L_SEQ + ct * 128)) * DD;
        const short* gM = Mbf + ((size_t)(b * L_SEQ + mc * 512)) * DD;
        #pragma unroll
        for (int ii = 0; ii < 8; ++ii) {
            int inst = w * 8 + ii;
            gl2lds16(gC + inst * 512 + l * 8, Cs + inst * 512);
        }
        #pragma unroll
        for (int ii = 0; ii < 4; ++ii) {
            int inst = w * 4 + ii;
            gl2lds16(gM + inst * 512 + l * 8, Ms[0] + inst * 512);
        }
    }

    __syncthreads();  // drains Cs + Ms[0]

    {   // prefetch step-1 M into Ms[1]; flies over the fragment hoist
        const short* gM = Mbf + ((size_t)(b * L_SEQ + mc * 512 + 64)) * DD;
        #pragma unroll
        for (int ii = 0; ii < 4; ++ii) {
            int inst = w * 4 + ii;
            gl2lds16(gM + inst * 512 + l * 8, Ms[1] + inst * 512);
        }
    }

    // Hoist invariant C A-fragments: 16 ds_read_b128 -> 64 VGPRs.
    bf16x8 af[4][4];
    #pragma unroll
    for (int ks = 0; ks < 4; ++ks) {
        int aoff = ((ks * 4 + q) ^ h) * 8;
        #pragma unroll
        for (int i = 0; i < 4; ++i)
            af[ks][i] = *(const bf16x8*)&Cs[(cw + i * 16 + a15) * 128 + aoff];
    }

    float ls[4][4] = {};  // partial L for c = ct*128 + cw + i*16 + q*4 + r

    for (int ms = 0; ms < 8; ++ms) {
        int bp = ms & 1;
        if (ms > 0) {
            __syncthreads();  // drains DMA into Ms[bp] (issued at ms-1)
            if (ms < 7) {     // prefetch next step into the OTHER buffer
                const short* gM = Mbf + ((size_t)(b * L_SEQ + mc * 512 + (ms + 1) * 64)) * DD;
                #pragma unroll
                for (int ii = 0; ii < 4; ++ii) {
                    int inst = w * 4 + ii;
                    gl2lds16(gM + inst * 512 + l * 8, Ms[bp ^ 1] + inst * 512);
                }
            }
        }

        f32x4 acc[4][2];
        #pragma unroll
        for (int i = 0; i < 4; ++i)
            #pragma unroll
            for (int j = 0; j < 2; ++j) {
                f32x4 z = {0.f, 0.f, 0.f, 0.f};
                acc[i][j] = z;
            }
        #pragma unroll
        for (int ks = 0; ks < 4; ++ks) {
            int aoff = ((ks * 4 + q) ^ h) * 8;
            bf16x8 bv[2];
            #pragma unroll
            for (int j = 0; j < 2; ++j)
                bv[j] = *(const bf16x8*)&Ms[bp][(mw + j * 16 + a15) * 128 + aoff];
            #pragma unroll
            for (int i = 0; i < 4; ++i)
                #pragma unroll
                for (int j = 0; j < 2; ++j)
                    acc[i][j] = __builtin_amdgcn_mfma_f32_16x16x32_bf16(af[ks][i], bv[j], acc[i][j], 0, 0, 0);
        }

        // E store straight from registers (b64, swizzled). D layout: row c = q*4+r
        // (4 consecutive c per lane), col m = a15.
        #pragma unroll
        for (int j = 0; j < 2; ++j) {
            int m = mc * 512 + ms * 64 + mw + j * 16 + a15;
            size_t rowb = ((size_t)(b * L_SEQ + m)) * L_SEQ;
            #pragma unroll
            for (int i = 0; i < 4; ++i) {
                bf16x4 pk;
                #pragma unroll
                for (int r = 0; r < 4; ++r) {
                    float e = __expf(acc[i][j][r] - SHIFT);
                    ls[i][r] += e;
                    pk[r] = f2bf(e);
                }
                int cq = ct * 128 + cw + i * 16 + q * 4;
                int chunk = cq >> 3;
                int pcc = (chunk & ~7) | ((chunk ^ m) & 7);
                *(bf16x4*)&Eg[rowb + pcc * 8 + (cq & 7)] = pk;
            }
        }
    }

    #pragma unroll
    for (int i = 0; i < 4; ++i)
        #pragma unroll
        for (int r = 0; r < 4; ++r) {
            float v = ls[i][r];
            v += __shfl_xor(v, 1);
            v += __shfl_xor(v, 2);
            v += __shfl_xor(v, 4);
            v += __shfl_xor(v, 8);
            ls[i][r] = v;
        }
    if (a15 == 0) {
        #pragma unroll
        for (int i = 0; i < 4; ++i) {
            int c = ct * 128 + cw + i * 16 + q * 4;
            #pragma unroll
            for (int r = 0; r < 4; ++r)
                atomicAdd(&Lg[(size_t)b * L_SEQ + c + r], ls[i][r]);
        }
    }
}

// grid = 8 b * 16 cc * 4 dq = 512 blocks, 256 thr. Reads bf16 Cbf (not fp32 ctx).
// CtL[b][d][c] = bf16(C[b][c][d] * invL[b][c]), transposed + swizzled by d&7.
__global__ __launch_bounds__(256, 2) void prep_kernel(const short* __restrict__ Cbf,
                                                      const float* __restrict__ Lg,
                                                      short* __restrict__ CtL) {
    __shared__ short Ts[128 * LDA];
    __shared__ float invLs[128];

    int bid = blockIdx.x;
    int b  = bid >> 6;
    int cc = (bid >> 2) & 15;
    int dq = bid & 3;
    int t = threadIdx.x;

    if (t < 128) invLs[t] = 1.0f / Lg[(size_t)b * L_SEQ + cc * 128 + t];
    __syncthreads();

    // Stage 128x128 tile from Cbf (unswizzle chunks), scale by invL, into Ts.
    #pragma unroll
    for (int it = 0; it < 8; ++it) {
        int cid = it * 256 + t;
        int r = cid >> 4;
        int lcs = cid & 15;                       // stored chunk index
        int lc = (lcs & 8) | ((lcs ^ r) & 7);     // logical chunk (XOR self-inverse)
        bf16x8 v = *(const bf16x8*)&Cbf[((size_t)(b * L_SEQ + cc * 128 + r)) * DD + lcs * 8];
        float il = invLs[r];
        bf16x8 sv;
        #pragma unroll
        for (int j = 0; j < 8; ++j) sv[j] = f2bf(bf2f(v[j]) * il);
        *(bf16x8*)&Ts[r * LDA + lc * 8] = sv;
    }
    __syncthreads();

    // Transposed, swizzled write of this block's 32 d-rows.
    int d = dq * 32 + (t >> 3);
    int key = d & 7;
    #pragma unroll
    for (int it = 0; it < 2; ++it) {
        int chIdx = (t & 7) + 8 * it;  // 0..15
        int c = chIdx * 8;
        bf16x8 v;
        #pragma unroll
        for (int j = 0; j < 8; ++j) v[j] = Ts[(c + j) * LDA + d];
        int pc = cc * 16 + (chIdx & 8) + ((chIdx ^ key) & 7);
        *(bf16x8*)&CtL[((size_t)(b * DD + d)) * L_SEQ + pc * 8] = v;
    }
}

// grid = 512 blocks, 256 thr. LDS 80 KB dbuf -> 2 blocks/CU. (R4/R8-proven form.)
__global__ __launch_bounds__(256, 2) void attend_kernel(const short* __restrict__ Eg,
                                                        const short* __restrict__ CtL,
                                                        const float* __restrict__ mn,
                                                        float* __restrict__ out) {
    __shared__ short Et2[2][32 * 128];
    __shared__ short Ct2[2][128 * 128];

    int bid = blockIdx.x;
    int mtile = bid & 63;
    int b = bid >> 6;
    int m0 = mtile * 32;
    int t = threadIdx.x;
    int w = t >> 6;
    int l = t & 63;
    int a15 = l & 15;
    int q = l >> 4;
    int h = a15 & 7;
    int lcc = l & 15;

    f32x4 acc[2][2] = {{{0.f,0.f,0.f,0.f},{0.f,0.f,0.f,0.f}},
                       {{0.f,0.f,0.f,0.f},{0.f,0.f,0.f,0.f}}};

    #pragma unroll
    for (int ii = 0; ii < 2; ++ii) {
        int inst = w * 2 + ii;
        gl2lds16(Eg + ((size_t)(b * L_SEQ + m0 + inst * 4 + q)) * L_SEQ + lcc * 8,
                 &Et2[0][inst * 512]);
    }
    #pragma unroll
    for (int ii = 0; ii < 8; ++ii) {
        int inst = w * 8 + ii;
        gl2lds16(CtL + ((size_t)(b * DD + inst * 4 + q)) * L_SEQ + lcc * 8,
                 &Ct2[0][inst * 512]);
    }

    for (int cs = 0; cs < 16; ++cs) {
        int bp = cs & 1;
        __syncthreads();  // drains loads into buf bp; buf bp^1 readers done last iter

        if (cs < 15) {
            int c0 = (cs + 1) * 128;
            #pragma unroll
            for (int ii = 0; ii < 2; ++ii) {
                int inst = w * 2 + ii;
                gl2lds16(Eg + ((size_t)(b * L_SEQ + m0 + inst * 4 + q)) * L_SEQ + c0 + lcc * 8,
                         &Et2[bp ^ 1][inst * 512]);
            }
            #pragma unroll
            for (int ii = 0; ii < 8; ++ii) {
                int inst = w * 8 + ii;
                gl2lds16(CtL + ((size_t)(b * DD + inst * 4 + q)) * L_SEQ + c0 + lcc * 8,
                         &Ct2[bp ^ 1][inst * 512]);
            }
        }

        const short* EtB = Et2[bp];
        const short* CtB = Ct2[bp];
        #pragma unroll
        for (int ks = 0; ks < 4; ++ks) {
            int aoff = ((ks * 4 + q) ^ h) * 8;
            bf16x8 a0 = *(const bf16x8*)&EtB[a15 * 128 + aoff];
            bf16x8 a1 = *(const bf16x8*)&EtB[(16 + a15) * 128 + aoff];
            bf16x8 b0 = *(const bf16x8*)&CtB[((w * 2 + 0) * 16 + a15) * 128 + aoff];
            bf16x8 b1 = *(const bf16x8*)&CtB[((w * 2 + 1) * 16 + a15) * 128 + aoff];
            acc[0][0] = __builtin_amdgcn_mfma_f32_16x16x32_bf16(a0, b0, acc[0][0], 0, 0, 0);
            acc[0][1] = __builtin_amdgcn_mfma_f32_16x16x32_bf16(a0, b1, acc[0][1], 0, 0, 0);
            acc[1][0] = __builtin_amdgcn_mfma_f32_16x16x32_bf16(a1, b0, acc[1][0], 0, 0, 0);
            acc[1][1] = __builtin_amdgcn_mfma_f32_16x16x32_bf16(a1, b1, acc[1][1], 0, 0, 0);
        }
    }

    // Epilogue: out = main(fp32) - O. D: col d = a15, row m = q*4+r.
    #pragma unroll
    for (int mg = 0; mg < 2; ++mg) {
        #pragma unroll
        for (int g = 0; g < 2; ++g) {
            int d = (w * 2 + g) * 16 + a15;
            #pragma unroll
            for (int r = 0; r < 4; ++r) {
                int m = m0 + mg * 16 + q * 4 + r;
                size_t idx = ((size_t)(b * L_SEQ + m)) * DD + d;
                out[idx] = mn[idx] - acc[mg][g][r];
            }
        }
    }
}

// ---------------------------------------------------------------------------
// Small-workspace fallback (round-2 kernels)
// ---------------------------------------------------------------------------

__global__ __launch_bounds__(256, 4) void stats_fb(const float* __restrict__ ctx,
                                                   const float* __restrict__ mn,
                                                   float* __restrict__ Lg) {
    __shared__ short Cs[64 * LDA];
    __shared__ short Ms[64 * LDA];

    int bid = blockIdx.x;
    int mc = bid & 3;
    int ct = (bid >> 2) & 31;
    int b  = bid >> 7;
    int t = threadIdx.x;
    int w = t >> 6;
    int l = t & 63;
    int a15 = l & 15;
    int q = l >> 4;

    stage_tile<256>(Cs, ctx + ((size_t)b * L_SEQ + ct * 64) * DD, 64 * DD, t);

    float ls[4] = {0.f, 0.f, 0.f, 0.f};
    for (int mt = 0; mt < 8; ++mt) {
        __syncthreads();
        int m0 = (mc * 8 + mt) * 64;
        stage_tile<256>(Ms, mn + ((size_t)b * L_SEQ + m0) * DD, 64 * DD, t);
        __syncthreads();

        f32x4 acc[4] = {{0.f,0.f,0.f,0.f},{0.f,0.f,0.f,0.f},{0.f,0.f,0.f,0.f},{0.f,0.f,0.f,0.f}};
        #pragma unroll
        for (int ks = 0; ks < 4; ++ks) {
            int k0 = ks * 32 + q * 8;
            bf16x8 a = *(const bf16x8*)&Cs[(w * 16 + a15) * LDA + k0];
            #pragma unroll
            for (int g = 0; g < 4; ++g) {
                bf16x8 bb = *(const bf16x8*)&Ms[(g * 16 + a15) * LDA + k0];
                acc[g] = __builtin_amdgcn_mfma_f32_16x16x32_bf16(a, bb, acc[g], 0, 0, 0);
            }
        }
        #pragma unroll
        for (int g = 0; g < 4; ++g)
            #pragma unroll
            for (int r = 0; r < 4; ++r)
                ls[r] += __expf(acc[g][r] - SHIFT);
    }

    #pragma unroll
    for (int r = 0; r < 4; ++r) {
        float v = ls[r];
        v += __shfl_xor(v, 1);
        v += __shfl_xor(v, 2);
        v += __shfl_xor(v, 4);
        v += __shfl_xor(v, 8);
        ls[r] = v;
    }
    if (a15 == 0) {
        int c = ct * 64 + w * 16 + q * 4;
        #pragma unroll
        for (int r = 0; r < 4; ++r)
            atomicAdd(&Lg[(size_t)b * L_SEQ + c + r], ls[r]);
    }
}

__global__ __launch_bounds__(1024, 4) void attend_fb(const float* __restrict__ ctx,
                                                     const float* __restrict__ mn,
                                                     const float* __restrict__ Lg,
                                                     float* __restrict__ out) {
    __shared__ short Mt[64 * LDA];
    __shared__ short Cs[128 * LDA];
    __shared__ short Ct[128 * LDA];
    __shared__ short Ps[64 * LDA];
    __shared__ float invLs[128];

    int bid = blockIdx.x;
    int mtile = bid & 31;
    int b = bid >> 5;
    int m0 = mtile * 64;
    int t = threadIdx.x;
    int w = t >> 6;
    int l = t & 63;
    int a15 = l & 15;
    int q = l >> 4;
    int mg = w & 3;
    int pg = w >> 2;

    stage_tile<1024>(Mt, mn + ((size_t)b * L_SEQ + m0) * DD, 64 * DD, t);

    f32x4 oacc[2] = {{0.f,0.f,0.f,0.f},{0.f,0.f,0.f,0.f}};

    for (int cs = 0; cs < 16; ++cs) {
        int c0 = cs * 128;
        __syncthreads();
        stage_tile<1024>(Cs, ctx + ((size_t)b * L_SEQ + c0) * DD, 128 * DD, t);
        if (t < 128) invLs[t] = 1.0f / Lg[(size_t)b * L_SEQ + c0 + t];
        __syncthreads();

        {
            int cc = t & 127;
            int d0 = (t >> 7) * 16;
            #pragma unroll
            for (int hh = 0; hh < 2; ++hh) {
                bf16x8 v = *(const bf16x8*)&Cs[cc * LDA + d0 + hh * 8];
                #pragma unroll
                for (int j = 0; j < 8; ++j)
                    Ct[(d0 + hh * 8 + j) * LDA + cc] = v[j];
            }
        }

        f32x4 sacc[2] = {{0.f,0.f,0.f,0.f},{0.f,0.f,0.f,0.f}};
        #pragma unroll
        for (int ks = 0; ks < 4; ++ks) {
            int k0 = ks * 32 + q * 8;
            bf16x8 a = *(const bf16x8*)&Mt[(mg * 16 + a15) * LDA + k0];
            #pragma unroll
            for (int g = 0; g < 2; ++g) {
                bf16x8 bb = *(const bf16x8*)&Cs[((pg * 2 + g) * 16 + a15) * LDA + k0];
                sacc[g] = __builtin_amdgcn_mfma_f32_16x16x32_bf16(a, bb, sacc[g], 0, 0, 0);
            }
        }
        #pragma unroll
        for (int g = 0; g < 2; ++g) {
            int cl = (pg * 2 + g) * 16 + a15;
            float il = invLs[cl];
            #pragma unroll
            for (int r = 0; r < 4; ++r) {
                float p = __expf(sacc[g][r] - SHIFT) * il;
                Ps[(mg * 16 + q * 4 + r) * LDA + cl] = f2bf(p);
            }
        }
        __syncthreads();

        #pragma unroll
        for (int ks = 0; ks < 4; ++ks) {
            int k0 = ks * 32 + q * 8;
            bf16x8 a = *(const bf16x8*)&Ps[(mg * 16 + a15) * LDA + k0];
            #pragma unroll
            for (int g = 0; g < 2; ++g) {
                bf16x8 bb = *(const bf16x8*)&Ct[((pg * 2 + g) * 16 + a15) * LDA + k0];
                oacc[g] = __builtin_amdgcn_mfma_f32_16x16x32_bf16(a, bb, oacc[g], 0, 0, 0);
            }
        }
    }

    #pragma unroll
    for (int g = 0; g < 2; ++g) {
        int dl = (pg * 2 + g) * 16 + a15;
        #pragma unroll
        for (int r = 0; r < 4; ++r) {
            int ml = mg * 16 + q * 4 + r;
            size_t idx = ((size_t)b * L_SEQ + m0 + ml) * DD + dl;
            out[idx] = mn[idx] - oacc[g][r];
        }
    }
}

// ---------------------------------------------------------------------------

extern "C" void kernel_launch(void* const* d_in, const int* in_sizes, int n_in,
                              void* d_out, int out_size, void* d_ws, size_t ws_size,
                              hipStream_t stream) {
    const float* ctx = (const float*)d_in[0];  // (B, Lc, D)
    const float* mn  = (const float*)d_in[1];  // (B, Lm, D)
    float* out = (float*)d_out;                // (B, Lm, D)

    // Workspace: Lg 64 KB | Cbf 4 MB | Mbf 4 MB | CtL 4 MB | E 67 MB
    const size_t LG_BYTES = (size_t)BATCH * L_SEQ * sizeof(float);
    const size_t BF_BYTES = (size_t)BATCH * L_SEQ * DD * sizeof(short);
    const size_t E_BYTES  = (size_t)BATCH * L_SEQ * L_SEQ * sizeof(short);
    const size_t NEED = LG_BYTES + 3 * BF_BYTES + E_BYTES;

    float* Lg = (float*)d_ws;

    if (ws_size >= NEED) {
        short* Cbf = (short*)((char*)d_ws + LG_BYTES);
        short* Mbf = (short*)((char*)d_ws + LG_BYTES + BF_BYTES);
        short* CtL = (short*)((char*)d_ws + LG_BYTES + 2 * BF_BYTES);
        short* Eg  = (short*)((char*)d_ws + LG_BYTES + 3 * BF_BYTES);
        convert_kernel<<<512, 256, 0, stream>>>(ctx, mn, Cbf, Mbf, Lg);
        stats_kernel<<<512, 256, 0, stream>>>(Cbf, Mbf, Lg, Eg);
        prep_kernel<<<512, 256, 0, stream>>>(Cbf, Lg, CtL);
        attend_kernel<<<512, 256, 0, stream>>>(Eg, CtL, mn, out);
    } else {
        int nL = BATCH * L_SEQ;
        zero_kernel<<<(nL + 255) / 256, 256, 0, stream>>>(Lg, nL);
        stats_fb<<<BATCH * 32 * 4, 256, 0, stream>>>(ctx, mn, Lg);
        attend_fb<<<BATCH * 32, 1024, 0, stream>>>(ctx, mn, Lg, out);
    }
}